// Round 10
// baseline (276.316 us; speedup 1.0000x reference)
//
#include <hip/hip_runtime.h>
#include <math.h>

#define NB 8
#define NA 720
#define NPAIR 360
#define ND 1024
#define NH 512
#define NW 512

// DS = 4/1024 -> 1/DS = 256. S0 = -2 + DS/2 -> -S0/DS = 511.5
#define DXF 0.00390625f
#define IMG_MIN_F (-1.0f)
#define DTH_D (3.14159265358979323846 / 720.0)

#define TI 32            // top-half i rows per block (plus 32 mirrored rows)
#define TJ 32            // j cols per block
#define WIN 128          // staged window elements (1 KB = one global_load_lds per wave)

typedef unsigned int uint32;
typedef __fp16 half2v __attribute__((ext_vector_type(2)));   // matches cvt_pkrtz return

// ---------------- Kernel 1: 11-tap conv on angle PAIR (p, 719-p) -> interleaved f16 G2 ----
// G2[b][p][d] (uint2): .x = pack(y_p[d], y_p[d+1]) f16x2 ; .y = same for row 719-p.
__global__ __launch_bounds__(256) void conv_kernel(const float* __restrict__ x,
                                                   const float* __restrict__ w,
                                                   uint2* __restrict__ G2) {
    int id = blockIdx.x;                  // b*360 + p
    int b = id / NPAIR;
    int p = id - b * NPAIR;
    const float* xr0 = x + ((size_t)b * NA + p) * ND;
    const float* xr1 = x + ((size_t)b * NA + (719 - p)) * ND;

    __shared__ float s[2][16 + ND];
    __shared__ unsigned short hh[2][ND + 8];
    __shared__ float wk[16];

    int tid = threadIdx.x;                // 256 threads
    if (tid < 16) { s[0][tid] = 0.0f; s[1][tid] = 0.0f; }
    if (tid < 11) wk[tid] = w[tid] * (float)DTH_D;
    if (tid < 8)  { hh[0][ND + tid] = 0; hh[1][ND + tid] = 0; }

    *(float4*)&s[0][16 + tid * 4] = ((const float4*)xr0)[tid];
    *(float4*)&s[1][16 + tid * 4] = ((const float4*)xr1)[tid];
    __syncthreads();

    int d0 = tid * 4;
#pragma unroll
    for (int r = 0; r < 2; ++r) {
        float o0 = 0.f, o1 = 0.f, o2 = 0.f, o3 = 0.f;
#pragma unroll
        for (int k = 0; k < 11; ++k) {
            float wv = wk[k];
            o0 = fmaf(wv, s[r][6 + d0 + k], o0);
            o1 = fmaf(wv, s[r][7 + d0 + k], o1);
            o2 = fmaf(wv, s[r][8 + d0 + k], o2);
            o3 = fmaf(wv, s[r][9 + d0 + k], o3);
        }
        union { _Float16 h[4]; uint2 u2; } pk;
        pk.h[0] = (_Float16)o0; pk.h[1] = (_Float16)o1;
        pk.h[2] = (_Float16)o2; pk.h[3] = (_Float16)o3;
        *(uint2*)&hh[r][d0] = pk.u2;      // 8B-aligned (2*d0 = 8*tid)
    }
    __syncthreads();

    uint32 a0 = *(const uint32*)&hh[0][d0];
    uint32 a1 = *(const uint32*)&hh[0][d0 + 2];
    uint32 a2 = *(const uint32*)&hh[0][d0 + 4];
    uint32 c0 = *(const uint32*)&hh[1][d0];
    uint32 c1 = *(const uint32*)&hh[1][d0 + 2];
    uint32 c2 = *(const uint32*)&hh[1][d0 + 4];

    uint2* gout = G2 + ((size_t)b * NPAIR + p) * ND + d0;
    gout[0] = make_uint2(a0, c0);
    gout[1] = make_uint2((a0 >> 16) | (a1 << 16), (c0 >> 16) | (c1 << 16));
    gout[2] = make_uint2(a1, c1);
    gout[3] = make_uint2((a1 >> 16) | (a2 << 16), (c1 >> 16) | (c2 << 16));
}

// ---------------- Kernel 2: fused per-(tile,pair) table: (ca, sa, 511.5-b1, 511.5-b2) ----
__global__ __launch_bounds__(256) void table_kernel(float4* __restrict__ tpr) {
    int idx = blockIdx.x * 256 + threadIdx.x;   // 360 pairs * 128 tiles = 46080
    if (idx >= NPAIR * 128) return;
    int p = idx >> 7;
    int t = idx & 127;
    float th = (float)((p + 0.5) * DTH_D);      // THETAS f64->f32 like reference
    double thd = (double)th;
    float ca = (float)(cos(thd) * 256.0);
    float sa = (float)(sin(thd) * 256.0);

    int it = t >> 4, jt = t & 15;
    int ibase = it * TI, jbase = jt * TJ;
    float pi_lo = IMG_MIN_F + (ibase + 0.5f) * DXF;
    float pi_hi = IMG_MIN_F + (ibase + TI - 0.5f) * DXF;
    float pj_lo = IMG_MIN_F + (jbase + 0.5f) * DXF;
    float pj_hi = IMG_MIN_F + (jbase + TJ - 0.5f) * DXF;
    float sj = fminf(pj_lo * sa, pj_hi * sa);
    float umin1 = 511.5f + fminf(pi_lo * ca, pi_hi * ca) + sj;
    float umin2 = 511.5f + fminf(-pi_lo * ca, -pi_hi * ca) + sj;
    int b1 = ((int)floorf(umin1) - 1) & ~3;     // 4-elem align -> 32B align in G2
    int b2 = ((int)floorf(umin2) - 1) & ~3;
    b1 = max(0, min(b1, ND - WIN));
    b2 = max(0, min(b2, ND - WIN));
    tpr[(size_t)t * NPAIR + p] =
        make_float4(ca, sa, 511.5f - (float)b1, 511.5f - (float)b2);
}

// ---------------- Kernel 3: backprojection, DMA windows + 2-deep LDS prefetch pipeline ---
// Per chunk: 8 pairs. PREF(k): compute u's + issue 4 ds_read_b64 into named regs.
// DOTS(k): weights + 8 v_dot2 (no DS). Interleaved 2-deep so every wave always has
// independent VALU between a read and its use -> DS latency off the critical path.

__device__ __forceinline__ void async_ld16(const float* g, float* l) {
    __builtin_amdgcn_global_load_lds((const __attribute__((address_space(1))) void*)g,
                                     (__attribute__((address_space(3))) void*)l,
                                     16, 0, 0);
}

#define WAIT_VM0_BARRIER() do { \
    asm volatile("" ::: "memory"); \
    __builtin_amdgcn_s_waitcnt(0x0F70); /* vmcnt(0) only */ \
    __builtin_amdgcn_s_barrier(); \
    asm volatile("" ::: "memory"); \
} while (0)

// acc(f32) += taps.lo16 * gf.lo + taps.hi16 * gf.hi   (one VOP3P dot2)
#define DOT2(acc_, taps_, gf_) \
    asm("v_dot2_f32_f16 %0, %1, %2, %0" : "+v"(acc_) : "v"(taps_), "v"(gf_))

__global__ __launch_bounds__(512, 8) void bp_kernel(const uint2* __restrict__ G2,
                                                    const float4* __restrict__ tpr,
                                                    float* __restrict__ out) {
    int bid = blockIdx.x;
    // XCD-chunked swizzle: XCD x -> all 128 tiles of batch x (2.95 MB G2 slice fits L2)
    int lb = (bid & 7) * 128 + (bid >> 3);
    int b = lb >> 7;
    int tile = lb & 127;
    int it = tile >> 4, jt = tile & 15;
    int ibase = it * TI, jbase = jt * TJ;

    int tid = threadIdx.x;
    int lane = tid & 63;
    int wv = tid >> 6;           // 0..7 -> stages pair c*8+wv
    int jj = lane & 31;
    int hi = lane >> 5;          // 0/1 -> +8 rows

    int j = jbase + jj;
    float pxj = IMG_MIN_F + (j + 0.5f) * DXF;
    int i0 = ibase + wv + 8 * hi;           // +16*r
    float pxi = IMG_MIN_F + (i0 + 0.5f) * DXF;

    __shared__ __align__(16) uint2 buf[2][8][2][WIN];   // 2*8*2*128*8 = 32768 B

    const uint2* gp = G2 + (size_t)b * (NPAIR * ND);
    const float4* tp = tpr + (size_t)tile * NPAIR;

    float accT0 = 0.f, accT1 = 0.f;         // pixels (i0, j), (i0+16, j)
    float accM0 = 0.f, accM1 = 0.f;         // pixels (511-i0, j), (511-i0-16, j)

    // pipeline state, explicitly named (static register allocation)
    uint2 Aq0, Aq1, Aq2, Aq3, Bq0, Bq1, Bq2, Bq3;
    float Au1a, Au1b, Au2a, Au2b, Bu1a, Bu1b, Bu2a, Bu2b;

#define STAGE(c_, bs_) do { \
    int p_ = (c_) * 8 + wv; \
    float4 t4_ = tp[p_]; \
    int b1_ = (int)(511.5f - t4_.z); \
    int b2_ = (int)(511.5f - t4_.w); \
    const float* g1_ = (const float*)(gp + (size_t)p_ * ND + b1_) + lane * 4; \
    const float* g2_ = (const float*)(gp + (size_t)p_ * ND + b2_) + lane * 4; \
    async_ld16(g1_, (float*)&buf[bs_][wv][0][0]); \
    async_ld16(g2_, (float*)&buf[bs_][wv][1][0]); \
} while (0)

#define PREF(kk_, S) do { \
    float4 t4_ = tp[c * 8 + (kk_)]; \
    float du_ = t4_.x * (16.0f * DXF); \
    S##u1a = fmaf(pxj, t4_.y, fmaf(pxi, t4_.x, t4_.z)); \
    S##u2a = fmaf(pxj, t4_.y, fmaf(pxi, -t4_.x, t4_.w)); \
    S##u1b = S##u1a + du_; \
    S##u2b = S##u2a - du_; \
    const uint2* W1_ = &buf[cur][kk_][0][0]; \
    const uint2* W2_ = &buf[cur][kk_][1][0]; \
    S##q0 = W1_[(int)S##u1a]; \
    S##q1 = W2_[(int)S##u2a]; \
    S##q2 = W1_[(int)S##u1b]; \
    S##q3 = W2_[(int)S##u2b]; \
} while (0)

#define DOTS(S) do { \
    float f_, g_; half2v pk_; \
    f_ = __builtin_amdgcn_fractf(S##u1a); g_ = 1.0f - f_; \
    pk_ = __builtin_amdgcn_cvt_pkrtz(g_, f_); \
    DOT2(accT0, S##q0.x, pk_); DOT2(accM0, S##q0.y, pk_); \
    f_ = __builtin_amdgcn_fractf(S##u2a); g_ = 1.0f - f_; \
    pk_ = __builtin_amdgcn_cvt_pkrtz(g_, f_); \
    DOT2(accM0, S##q1.x, pk_); DOT2(accT0, S##q1.y, pk_); \
    f_ = __builtin_amdgcn_fractf(S##u1b); g_ = 1.0f - f_; \
    pk_ = __builtin_amdgcn_cvt_pkrtz(g_, f_); \
    DOT2(accT1, S##q2.x, pk_); DOT2(accM1, S##q2.y, pk_); \
    f_ = __builtin_amdgcn_fractf(S##u2b); g_ = 1.0f - f_; \
    pk_ = __builtin_amdgcn_cvt_pkrtz(g_, f_); \
    DOT2(accM1, S##q3.x, pk_); DOT2(accT1, S##q3.y, pk_); \
} while (0)

    STAGE(0, 0);
    WAIT_VM0_BARRIER();

    for (int c = 0; c < 45; ++c) {
        int cur = c & 1;
        if (c + 1 < 45) STAGE(c + 1, cur ^ 1);   // 2 async DMAs per wave
        PREF(0, A);
        PREF(1, B);
        DOTS(A);        // k0  (A reads issued 1 phase ago, 8 reads in flight behind)
        PREF(2, A);
        DOTS(B);        // k1
        PREF(3, B);
        DOTS(A);        // k2
        PREF(4, A);
        DOTS(B);        // k3
        PREF(5, B);
        DOTS(A);        // k4
        PREF(6, A);
        DOTS(B);        // k5
        PREF(7, B);
        DOTS(A);        // k6
        DOTS(B);        // k7
        WAIT_VM0_BARRIER();                      // drain DMAs, swap buffers
    }

    float* orow = out + (size_t)b * (NH * NW);
    {
        int i = i0;
        orow[i * NW + j] = accT0;
        orow[(511 - i) * NW + j] = accM0;
        i = i0 + 16;
        orow[i * NW + j] = accT1;
        orow[(511 - i) * NW + j] = accM1;
    }
#undef STAGE
#undef PREF
#undef DOTS
}

extern "C" void kernel_launch(void* const* d_in, const int* in_sizes, int n_in,
                              void* d_out, int out_size, void* d_ws, size_t ws_size,
                              hipStream_t stream) {
    const float* x = (const float*)d_in[0];      // [8,1,720,1024] f32
    const float* w = (const float*)d_in[1];      // [1,1,1,11] f32
    float* out = (float*)d_out;                  // [8,1,512,512] f32

    uint2* G2 = (uint2*)d_ws;                    // 8*360*1024*8 B = 23.6 MB
    float4* tpr = (float4*)((float*)d_ws + (size_t)NB * NPAIR * ND * 2);  // 737 KB

    conv_kernel<<<dim3(NB * NPAIR), dim3(256), 0, stream>>>(x, w, G2);
    table_kernel<<<dim3(180), dim3(256), 0, stream>>>(tpr);
    bp_kernel<<<dim3(1024), dim3(512), 0, stream>>>(G2, tpr, out);
}